// Round 2
// baseline (135434.937 us; speedup 1.0000x reference)
//
#include <hip/hip_runtime.h>
#include <hip/hip_cooperative_groups.h>
#include <math.h>

namespace cg = cooperative_groups;

#define BATCH 8
#define SEQ_T 2048
#define DIM 1024
#define TWO_D 2048
#define NWG 256
#define NTHR 1024
#define O_PER_WG 8   // h columns per WG  (TWO_D / NWG)
#define C_PER_WG 4   // out columns per WG (DIM / NWG)

__device__ __forceinline__ float gelu_erf(float v) {
    return 0.5f * v * (1.0f + erff(v * 0.70710678118654752f));
}

__global__ void __launch_bounds__(NTHR) gru_persistent(
    const float* __restrict__ x,   // [B, T, D]
    const float* __restrict__ W1,  // [2D, 2D] row-major [out,in]
    const float* __restrict__ b1,  // [2D]
    const float* __restrict__ W2,  // [D, 2D]
    const float* __restrict__ b2,  // [D]
    float* __restrict__ out,       // [B, T, D]
    float* __restrict__ ws)
{
    // 96 KB static LDS (gfx950 allows up to 160 KB/WG); 1 WG/CU.
    __shared__ float w1s[O_PER_WG * TWO_D];   // 64 KB
    __shared__ float w2s[C_PER_WG * TWO_D];   // 32 KB

    const int g   = blockIdx.x;
    const int tid = threadIdx.x;

    float* mem = ws;               // [B][D]   32 KB
    float* h   = ws + BATCH * DIM; // [B][2D]  64 KB

    // ---- stage this WG's weight slice into LDS (once) ----
    {
        const float4* src1 = (const float4*)(W1 + (size_t)g * O_PER_WG * TWO_D);
        float4* dst1 = (float4*)w1s;
        for (int i = tid; i < O_PER_WG * TWO_D / 4; i += NTHR) dst1[i] = src1[i];
        const float4* src2 = (const float4*)(W2 + (size_t)g * C_PER_WG * TWO_D);
        float4* dst2 = (float4*)w2s;
        for (int i = tid; i < C_PER_WG * TWO_D / 4; i += NTHR) dst2[i] = src2[i];
    }
    // ---- zero the memory state (ws is re-poisoned before every launch) ----
    {
        int gt = g * NTHR + tid;
        if (gt < BATCH * DIM) mem[gt] = 0.0f;
    }
    cg::this_grid().sync();

    // phase-1 mapping: 64 pairs (b, o_local) x 16 k-subs
    const int p1  = tid >> 4;
    const int s1  = tid & 15;
    const int pb1 = p1 & 7;        // batch row
    const int ol  = p1 >> 3;       // local h column 0..7
    const int oco = g * O_PER_WG + ol;

    // phase-2 mapping: 32 pairs (b, c_local) x 32 k-subs
    const int p2  = tid >> 5;
    const int s2  = tid & 31;
    const int pb2 = p2 & 7;
    const int cl  = p2 >> 3;       // local out column 0..3
    const int cco = g * C_PER_WG + cl;

    const float bias1 = b1[oco];
    const float bias2 = b2[cco];

    const float4* wv1 = (const float4*)(w1s + (size_t)ol * TWO_D);  // 512 float4
    const float4* wv2 = (const float4*)(w2s + (size_t)cl * TWO_D);  // 512 float4
    const float4* mv  = (const float4*)(mem + (size_t)pb1 * DIM);   // 256 float4
    const float4* hv  = (const float4*)(h + (size_t)pb2 * TWO_D);   // 512 float4

    for (int t = 0; t < SEQ_T; ++t) {
        // ---------- phase 1: h = gelu([x_t, mem] @ W1.T + b1), our 8 cols ----------
        {
            const float4* xv = (const float4*)(x + ((size_t)pb1 * SEQ_T + t) * DIM);
            float4 a4 = {0.f, 0.f, 0.f, 0.f};
            #pragma unroll 8
            for (int j = 0; j < 16; ++j) {
                int f = j * 16 + s1;              // 0..255 (x part)
                float4 a = xv[f], w = wv1[f];
                a4.x += a.x * w.x; a4.y += a.y * w.y;
                a4.z += a.z * w.z; a4.w += a.w * w.w;
            }
            #pragma unroll 8
            for (int j = 0; j < 16; ++j) {
                int f = j * 16 + s1;              // 0..255 (mem part)
                float4 a = mv[f], w = wv1[256 + f];
                a4.x += a.x * w.x; a4.y += a.y * w.y;
                a4.z += a.z * w.z; a4.w += a.w * w.w;
            }
            float acc = (a4.x + a4.y) + (a4.z + a4.w);
            acc += __shfl_xor(acc, 1);
            acc += __shfl_xor(acc, 2);
            acc += __shfl_xor(acc, 4);
            acc += __shfl_xor(acc, 8);
            if (s1 == 0) {
                h[(size_t)pb1 * TWO_D + oco] = gelu_erf(acc + bias1);
            }
        }
        cg::this_grid().sync();

        // ---------- phase 2: proposed = h @ W2.T + b2; gated memory update ----------
        {
            float4 a4 = {0.f, 0.f, 0.f, 0.f};
            #pragma unroll 8
            for (int j = 0; j < 16; ++j) {
                int f = j * 32 + s2;              // 0..511
                float4 a = hv[f], w = wv2[f];
                a4.x += a.x * w.x; a4.y += a.y * w.y;
                a4.z += a.z * w.z; a4.w += a.w * w.w;
            }
            float acc = (a4.x + a4.y) + (a4.z + a4.w);
            acc += __shfl_xor(acc, 1);
            acc += __shfl_xor(acc, 2);
            acc += __shfl_xor(acc, 4);
            acc += __shfl_xor(acc, 8);
            acc += __shfl_xor(acc, 16);
            if (s2 == 0) {
                float prop = acc + bias2;
                float gate = 1.0f / (1.0f + expf(-prop));
                float mold = mem[(size_t)pb2 * DIM + cco];
                float mnew = mold * (1.0f - gate) + prop * gate;
                mem[(size_t)pb2 * DIM + cco] = mnew;
                out[((size_t)pb2 * SEQ_T + t) * DIM + cco] = mnew;
            }
        }
        cg::this_grid().sync();
    }
}

extern "C" void kernel_launch(void* const* d_in, const int* in_sizes, int n_in,
                              void* d_out, int out_size, void* d_ws, size_t ws_size,
                              hipStream_t stream) {
    const float* x  = (const float*)d_in[0];
    const float* W1 = (const float*)d_in[1];
    const float* b1 = (const float*)d_in[2];
    const float* W2 = (const float*)d_in[3];
    const float* b2 = (const float*)d_in[4];
    float* out = (float*)d_out;
    float* ws  = (float*)d_ws;

    void* args[] = {(void*)&x, (void*)&W1, (void*)&b1, (void*)&W2, (void*)&b2,
                    (void*)&out, (void*)&ws};
    (void)hipLaunchCooperativeKernel((const void*)gru_persistent,
                                     dim3(NWG), dim3(NTHR), args, 0, stream);
}

// Round 3
// 45349.783 us; speedup vs baseline: 2.9865x; 2.9865x over previous
//
#include <hip/hip_runtime.h>
#include <hip/hip_cooperative_groups.h>
#include <hip/hip_bf16.h>
#include <math.h>

namespace cg = cooperative_groups;

#define BATCH 8
#define SEQ_T 2048
#define DIM 1024
#define TWO_D 2048
#define NWG 256
#define NTHR 1024
#define O_PER_WG 8   // h columns per WG  (TWO_D / NWG)
#define C_PER_WG 4   // out columns per WG (DIM / NWG)
#define SCOPE __HIP_MEMORY_SCOPE_AGENT

__device__ __forceinline__ float gelu_erf(float v) {
    return 0.5f * v * (1.0f + erff(v * 0.70710678118654752f));
}

__device__ __forceinline__ void st_agent(float* p, float v) {
    __hip_atomic_store(p, v, __ATOMIC_RELAXED, SCOPE);
}
__device__ __forceinline__ float ld_agent(const float* p) {
    return __hip_atomic_load(p, __ATOMIC_RELAXED, SCOPE);
}
__device__ __forceinline__ float bf2f(unsigned short u) {
    union { unsigned int i; float f; } c; c.i = ((unsigned int)u) << 16; return c.f;
}

// Monotonic-epoch grid barrier. Safe: a WG exits epoch e only when counter ==
// NWG*e, which requires every WG to have arrived at e (each WG adds once per
// epoch and can be at most one epoch ahead). Counter never resets -> no race.
__device__ __forceinline__ void gbar(unsigned* ctr, unsigned target) {
    __syncthreads();   // drains this WG's vmcnt (write-through stores now visible)
    if (threadIdx.x == 0) {
        __hip_atomic_fetch_add(ctr, 1u, __ATOMIC_RELAXED, SCOPE);
        while (__hip_atomic_load(ctr, __ATOMIC_RELAXED, SCOPE) < target) {
            __builtin_amdgcn_s_sleep(1);
        }
    }
    __syncthreads();
}

__global__ void __launch_bounds__(NTHR) gru_persistent(
    const float* __restrict__ x,   // [B, T, D]
    const float* __restrict__ W1,  // [2D, 2D]
    const float* __restrict__ b1,  // [2D]
    const float* __restrict__ W2,  // [D, 2D]
    const float* __restrict__ b2,  // [D]
    float* __restrict__ out,       // [B, T, D]
    float* __restrict__ ws)
{
    __shared__ float w1s[O_PER_WG * TWO_D];   // 64 KB
    __shared__ float w2s[C_PER_WG * TWO_D];   // 32 KB
    __shared__ float stage[BATCH * DIM];      // 32 KB: mem(fp32) in ph1, h(bf16) in ph2

    const int g   = blockIdx.x;
    const int tid = threadIdx.x;

    unsigned* ctr = (unsigned*)ws;
    float* mem = ws + 1024;                 // [B][D]
    float* h   = ws + 1024 + BATCH * DIM;   // [B][2D]

    // ---- stage weights into LDS (once) ----
    {
        const float4* src1 = (const float4*)(W1 + (size_t)g * O_PER_WG * TWO_D);
        float4* dst1 = (float4*)w1s;
        for (int i = tid; i < O_PER_WG * TWO_D / 4; i += NTHR) dst1[i] = src1[i];
        const float4* src2 = (const float4*)(W2 + (size_t)g * C_PER_WG * TWO_D);
        float4* dst2 = (float4*)w2s;
        for (int i = tid; i < C_PER_WG * TWO_D / 4; i += NTHR) dst2[i] = src2[i];
    }
    // ---- init barrier counter + zero memory state (ws is poisoned each launch) ----
    if (g == 0) {
        if (tid == 0) __hip_atomic_store(ctr, 0u, __ATOMIC_RELAXED, SCOPE);
        for (int i = tid; i < BATCH * DIM; i += NTHR) st_agent(&mem[i], 0.0f);
    }
    cg::this_grid().sync();   // the one expensive sync: orders init for everyone

    // phase-1 mapping: 64 pairs (b, o_local) x 16 k-subs
    const int p1  = tid >> 4;
    const int s1  = tid & 15;
    const int pb1 = p1 & 7;
    const int ol  = p1 >> 3;
    const int oco = g * O_PER_WG + ol;

    // phase-2 mapping: 32 pairs (b, c_local) x 32 k-subs
    const int p2  = tid >> 5;
    const int s2  = tid & 31;
    const int pb2 = p2 & 7;
    const int cl  = p2 >> 3;
    const int cco = g * C_PER_WG + cl;

    const float bias1 = b1[oco];
    const float bias2 = b2[cco];
    float mymem = 0.0f;   // owner-register copy of mem[pb2][cco] (s2==0 threads)

    const float4* wv1 = (const float4*)(w1s + (size_t)ol * TWO_D);
    const float4* wv2 = (const float4*)(w2s + (size_t)cl * TWO_D);
    const float4* mv  = (const float4*)(stage + (size_t)pb1 * DIM);

    unsigned epoch = 0;

    for (int t = 0; t < SEQ_T; ++t) {
        // ---- stage mem(t-1) into LDS (fp32), coalesced agent loads ----
        #pragma unroll
        for (int k = 0; k < BATCH * DIM / NTHR; ++k) {
            int idx = k * NTHR + tid;
            stage[idx] = ld_agent(&mem[idx]);
        }
        __syncthreads();

        // ---- phase 1: h = gelu([x_t, mem] @ W1.T + b1) ----
        {
            const float4* xv = (const float4*)(x + ((size_t)pb1 * SEQ_T + t) * DIM);
            float4 a4 = {0.f, 0.f, 0.f, 0.f};
            #pragma unroll 8
            for (int j = 0; j < 16; ++j) {
                int f = j * 16 + s1;
                float4 a = xv[f], w = wv1[f];
                a4.x += a.x * w.x; a4.y += a.y * w.y;
                a4.z += a.z * w.z; a4.w += a.w * w.w;
            }
            #pragma unroll 8
            for (int j = 0; j < 16; ++j) {
                int f = j * 16 + s1;
                float4 a = mv[f], w = wv1[256 + f];
                a4.x += a.x * w.x; a4.y += a.y * w.y;
                a4.z += a.z * w.z; a4.w += a.w * w.w;
            }
            float acc = (a4.x + a4.y) + (a4.z + a4.w);
            acc += __shfl_xor(acc, 1);
            acc += __shfl_xor(acc, 2);
            acc += __shfl_xor(acc, 4);
            acc += __shfl_xor(acc, 8);
            if (s1 == 0) {
                st_agent(&h[(size_t)pb1 * TWO_D + oco], gelu_erf(acc + bias1));
            }
        }
        gbar(ctr, ++epoch * NWG);

        // ---- stage h(t) into LDS as bf16 ----
        {
            __hip_bfloat16* hs = (__hip_bfloat16*)stage;
            #pragma unroll
            for (int k = 0; k < BATCH * TWO_D / NTHR; ++k) {
                int idx = k * NTHR + tid;
                hs[idx] = __float2bfloat16(ld_agent(&h[idx]));
            }
        }
        __syncthreads();

        // ---- phase 2: proposed = h @ W2.T + b2; gated memory update ----
        {
            const ushort4* hv4 = (const ushort4*)((const unsigned short*)stage
                                                  + (size_t)pb2 * TWO_D);
            float4 a4 = {0.f, 0.f, 0.f, 0.f};
            #pragma unroll 8
            for (int j = 0; j < 16; ++j) {
                int f = j * 32 + s2;
                ushort4 hq = hv4[f];
                float4 w = wv2[f];
                a4.x += bf2f(hq.x) * w.x; a4.y += bf2f(hq.y) * w.y;
                a4.z += bf2f(hq.z) * w.z; a4.w += bf2f(hq.w) * w.w;
            }
            float acc = (a4.x + a4.y) + (a4.z + a4.w);
            acc += __shfl_xor(acc, 1);
            acc += __shfl_xor(acc, 2);
            acc += __shfl_xor(acc, 4);
            acc += __shfl_xor(acc, 8);
            acc += __shfl_xor(acc, 16);
            if (s2 == 0) {
                float prop = acc + bias2;
                float gate = 1.0f / (1.0f + expf(-prop));
                mymem = mymem * (1.0f - gate) + prop * gate;
                st_agent(&mem[(size_t)pb2 * DIM + cco], mymem);
                out[((size_t)pb2 * SEQ_T + t) * DIM + cco] = mymem;
            }
        }
        gbar(ctr, ++epoch * NWG);
    }
}

extern "C" void kernel_launch(void* const* d_in, const int* in_sizes, int n_in,
                              void* d_out, int out_size, void* d_ws, size_t ws_size,
                              hipStream_t stream) {
    const float* x  = (const float*)d_in[0];
    const float* W1 = (const float*)d_in[1];
    const float* b1 = (const float*)d_in[2];
    const float* W2 = (const float*)d_in[3];
    const float* b2 = (const float*)d_in[4];
    float* out = (float*)d_out;
    float* ws  = (float*)d_ws;

    void* args[] = {(void*)&x, (void*)&W1, (void*)&b1, (void*)&W2, (void*)&b2,
                    (void*)&out, (void*)&ws};
    (void)hipLaunchCooperativeKernel((const void*)gru_persistent,
                                     dim3(NWG), dim3(NTHR), args, 0, stream);
}

// Round 4
// 30441.061 us; speedup vs baseline: 4.4491x; 1.4898x over previous
//
#include <hip/hip_runtime.h>
#include <hip/hip_cooperative_groups.h>
#include <math.h>

namespace cg = cooperative_groups;

#define BATCH 8
#define SEQ_T 2048
#define DIM 1024
#define TWO_D 2048
#define NWG 256
#define NTHR 1024
#define O_PER_WG 8   // h columns per WG  (TWO_D / NWG)
#define C_PER_WG 4   // out columns per WG (DIM / NWG)
#define NCTR 64
#define CTR_STRIDE 32     // uints -> 128 B spacing
#define SCOPE __HIP_MEMORY_SCOPE_AGENT

__device__ __forceinline__ float gelu_erf(float v) {
    return 0.5f * v * (1.0f + erff(v * 0.70710678118654752f));
}
__device__ __forceinline__ void st_agent(float* p, float v) {
    __hip_atomic_store(p, v, __ATOMIC_RELAXED, SCOPE);
}
__device__ __forceinline__ float ld_agent(const float* p) {
    return __hip_atomic_load(p, __ATOMIC_RELAXED, SCOPE);
}
__device__ __forceinline__ void st_agent_u(unsigned* p, unsigned v) {
    __hip_atomic_store(p, v, __ATOMIC_RELAXED, SCOPE);
}
__device__ __forceinline__ unsigned ld_agent_u(const unsigned* p) {
    return __hip_atomic_load(p, __ATOMIC_RELAXED, SCOPE);
}
__device__ __forceinline__ unsigned rtne_bf16(float f) {
    union { float f; unsigned u; } c; c.f = f;
    return (c.u + 0x7fffu + ((c.u >> 16) & 1u)) >> 16;   // RTNE to bf16, as ushort
}

__global__ void __launch_bounds__(NTHR) gru_persistent(
    const float* __restrict__ x,   // [B, T, D]
    const float* __restrict__ W1,  // [2D, 2D]
    const float* __restrict__ b1,  // [2D]
    const float* __restrict__ W2,  // [D, 2D]
    const float* __restrict__ b2,  // [D]
    float* __restrict__ out,       // [B, T, D]
    float* __restrict__ ws)
{
    __shared__ float w1s[O_PER_WG * TWO_D];   // 64 KB
    __shared__ float w2s[C_PER_WG * TWO_D];   // 32 KB
    __shared__ float stage[BATCH * DIM];      // 32 KB: mem fp32 (ph1) / h bf16-pairs (ph2)
    __shared__ float hstash[O_PER_WG * BATCH];

    const int g   = blockIdx.x;
    const int tid = threadIdx.x;

    unsigned* ctr  = (unsigned*)ws;                       // 64 ctrs * 128 B = 8 KB
    float*    memg = ws + NCTR * CTR_STRIDE;              // [8][1024] fp32
    unsigned* hg   = (unsigned*)(memg + BATCH * DIM);     // [8][1024] bf16-pairs

    // ---- stage weights into LDS (once) ----
    {
        const float4* src1 = (const float4*)(W1 + (size_t)g * O_PER_WG * TWO_D);
        float4* dst1 = (float4*)w1s;
        for (int i = tid; i < O_PER_WG * TWO_D / 4; i += NTHR) dst1[i] = src1[i];
        const float4* src2 = (const float4*)(W2 + (size_t)g * C_PER_WG * TWO_D);
        float4* dst2 = (float4*)w2s;
        for (int i = tid; i < C_PER_WG * TWO_D / 4; i += NTHR) dst2[i] = src2[i];
    }
    if (g == 0 && tid < NCTR) st_agent_u(&ctr[tid * CTR_STRIDE], 0u);
    __syncthreads();   // w1s ready (needed below for the t=0 x-partial)

    // phase-1 mapping: 64 pairs (b, o_local) x 16 k-subs
    const int p1  = tid >> 4;
    const int s1  = tid & 15;
    const int pb1 = p1 & 7;
    const int ol  = p1 >> 3;
    const int oco = g * O_PER_WG + ol;

    // phase-2 mapping: 32 pairs (b, c_local) x 32 k-subs
    const int p2  = tid >> 5;
    const int s2  = tid & 31;
    const int pb2 = p2 & 7;
    const int cl  = p2 >> 3;
    const int cco = g * C_PER_WG + cl;

    const float bias1 = b1[oco];
    const float bias2 = b2[cco];
    float mymem = 0.0f;

    const float4* wv1  = (const float4*)(w1s + (size_t)ol * TWO_D);  // x-part rows
    const float4* wv1m = wv1 + 256;                                  // mem-part rows
    const float2* w2p  = (const float2*)(w2s + (size_t)cl * TWO_D);  // 1024 pairs

    // x-partial for step t (no dependence on mem) — computed one step ahead
    auto xpart = [&](int t) -> float4 {
        const float4* xv = (const float4*)(x + ((size_t)pb1 * SEQ_T + t) * DIM);
        float4 a = {0.f, 0.f, 0.f, 0.f};
        #pragma unroll
        for (int j = 0; j < 16; ++j) {
            int f = j * 16 + s1;
            float4 xa = xv[f], w = wv1[f];
            a.x += xa.x * w.x; a.y += xa.y * w.y;
            a.z += xa.z * w.z; a.w += xa.w * w.w;
        }
        return a;
    };
    float4 a4x = xpart(0);

    cg::this_grid().sync();   // once: orders counter init

    unsigned bk = 0;   // global barrier index

    for (int t = 0; t < SEQ_T; ++t) {
        // ---- stage mem(t-1) fp32 into LDS ----
        if (t == 0) {
            #pragma unroll
            for (int k = 0; k < BATCH * DIM / NTHR; ++k) stage[k * NTHR + tid] = 0.f;
        } else {
            #pragma unroll
            for (int k = 0; k < BATCH * DIM / NTHR; ++k) {
                int i = k * NTHR + tid;
                stage[i] = ld_agent(&memg[i]);
            }
        }
        __syncthreads();

        // ---- phase 1: h = gelu(x-part + mem-part + b1) ----
        {
            const float4* mv = (const float4*)(stage + (size_t)pb1 * DIM);
            float4 a4 = a4x;
            #pragma unroll
            for (int j = 0; j < 16; ++j) {
                int f = j * 16 + s1;
                float4 m = mv[f], w = wv1m[f];
                a4.x += m.x * w.x; a4.y += m.y * w.y;
                a4.z += m.z * w.z; a4.w += m.w * w.w;
            }
            float acc = (a4.x + a4.y) + (a4.z + a4.w);
            acc += __shfl_xor(acc, 1);
            acc += __shfl_xor(acc, 2);
            acc += __shfl_xor(acc, 4);
            acc += __shfl_xor(acc, 8);
            if (s1 == 0) hstash[ol * BATCH + pb1] = gelu_erf(acc + bias1);
        }
        __syncthreads();
        // pack h into bf16 pairs and publish (32 uints per WG)
        if (tid < 32) {
            int b = tid & 7, j = tid >> 3;   // j = 0..3 local pair
            float h0 = hstash[(2 * j) * BATCH + b];
            float h1 = hstash[(2 * j + 1) * BATCH + b];
            unsigned u = rtne_bf16(h0) | (rtne_bf16(h1) << 16);
            st_agent_u(&hg[(size_t)b * (TWO_D / 2) + g * 4 + j], u);
        }
        __syncthreads();   // drain publish stores (per-wave vmcnt(0) before barrier)
        if (tid == 0)
            __hip_atomic_fetch_add(&ctr[(g & (NCTR - 1)) * CTR_STRIDE], 1u,
                                   __ATOMIC_RELAXED, SCOPE);
        ++bk;
        // overlap: next step's x-partial while other WGs arrive
        if (t + 1 < SEQ_T) a4x = xpart(t + 1);
        if (tid < 64) {
            const unsigned tgt = bk * NWG;
            for (;;) {
                unsigned v = ld_agent_u(&ctr[tid * CTR_STRIDE]);
                v += __shfl_xor(v, 1);  v += __shfl_xor(v, 2);
                v += __shfl_xor(v, 4);  v += __shfl_xor(v, 8);
                v += __shfl_xor(v, 16); v += __shfl_xor(v, 32);
                if (v >= tgt) break;
            }
        }
        __syncthreads();

        // ---- stage h(t) packed bf16 into LDS ----
        {
            unsigned* hs = (unsigned*)stage;
            #pragma unroll
            for (int k = 0; k < BATCH * (TWO_D / 2) / NTHR; ++k) {
                int i = k * NTHR + tid;
                hs[i] = ld_agent_u(&hg[i]);
            }
        }
        __syncthreads();

        // ---- phase 2: proposed = h @ W2.T + b2; gated memory update ----
        {
            const unsigned* hrow = (const unsigned*)stage + (size_t)pb2 * (TWO_D / 2);
            float accx = 0.f, accy = 0.f;
            #pragma unroll
            for (int j = 0; j < 32; ++j) {
                int f = j * 32 + s2;
                unsigned u = hrow[f];
                float2 w = w2p[f];
                union { unsigned u; float f; } lo, hi;
                lo.u = u << 16;
                hi.u = u & 0xffff0000u;
                accx += lo.f * w.x;
                accy += hi.f * w.y;
            }
            float acc = accx + accy;
            acc += __shfl_xor(acc, 1);
            acc += __shfl_xor(acc, 2);
            acc += __shfl_xor(acc, 4);
            acc += __shfl_xor(acc, 8);
            acc += __shfl_xor(acc, 16);
            if (s2 == 0) {
                float prop = acc + bias2;
                float gate = 1.0f / (1.0f + expf(-prop));
                mymem = mymem * (1.0f - gate) + prop * gate;
                st_agent(&memg[(size_t)pb2 * DIM + cco], mymem);
                out[((size_t)pb2 * SEQ_T + t) * DIM + cco] = mymem;
            }
        }
        __syncthreads();   // drain mem stores across all waves
        if (tid == 0)
            __hip_atomic_fetch_add(&ctr[(g & (NCTR - 1)) * CTR_STRIDE], 1u,
                                   __ATOMIC_RELAXED, SCOPE);
        ++bk;
        if (tid < 64) {
            const unsigned tgt = bk * NWG;
            for (;;) {
                unsigned v = ld_agent_u(&ctr[tid * CTR_STRIDE]);
                v += __shfl_xor(v, 1);  v += __shfl_xor(v, 2);
                v += __shfl_xor(v, 4);  v += __shfl_xor(v, 8);
                v += __shfl_xor(v, 16); v += __shfl_xor(v, 32);
                if (v >= tgt) break;
            }
        }
        __syncthreads();
    }
}

extern "C" void kernel_launch(void* const* d_in, const int* in_sizes, int n_in,
                              void* d_out, int out_size, void* d_ws, size_t ws_size,
                              hipStream_t stream) {
    const float* x  = (const float*)d_in[0];
    const float* W1 = (const float*)d_in[1];
    const float* b1 = (const float*)d_in[2];
    const float* W2 = (const float*)d_in[3];
    const float* b2 = (const float*)d_in[4];
    float* out = (float*)d_out;
    float* ws  = (float*)d_ws;

    void* args[] = {(void*)&x, (void*)&W1, (void*)&b1, (void*)&W2, (void*)&b2,
                    (void*)&out, (void*)&ws};
    (void)hipLaunchCooperativeKernel((const void*)gru_persistent,
                                     dim3(NWG), dim3(NTHR), args, 0, stream);
}

// Round 6
// 22728.780 us; speedup vs baseline: 5.9587x; 1.3393x over previous
//
#include <hip/hip_runtime.h>
#include <hip/hip_cooperative_groups.h>
#include <math.h>

namespace cg = cooperative_groups;

#define BATCH 8
#define SEQ_T 2048
#define DIM 1024
#define TWO_D 2048
#define NWG 256
#define NTHR 1024
#define GWG 128      // WGs per group
#define RPG 4        // batch rows per group
#define O_PER 16     // h columns per WG   (TWO_D / GWG)
#define C_PER 8      // out columns per WG (DIM / GWG)
#define NCTR 64
#define CTR_STRIDE 32   // uints -> 128 B spacing
#define SCOPE __HIP_MEMORY_SCOPE_AGENT

__device__ __forceinline__ float gelu_erf(float v) {
    return 0.5f * v * (1.0f + erff(v * 0.70710678118654752f));
}
__device__ __forceinline__ void st_agent_u(unsigned* p, unsigned v) {
    __hip_atomic_store(p, v, __ATOMIC_RELAXED, SCOPE);
}
__device__ __forceinline__ unsigned ld_agent_u(const unsigned* p) {
    return __hip_atomic_load(p, __ATOMIC_RELAXED, SCOPE);
}
__device__ __forceinline__ unsigned rtne_bf16(float f) {
    union { float f; unsigned u; } c; c.f = f;
    return (c.u + 0x7fffu + ((c.u >> 16) & 1u)) >> 16;
}
__device__ __forceinline__ unsigned pack2(float a, float b) {
    return rtne_bf16(a) | (rtne_bf16(b) << 16);
}
__device__ __forceinline__ float lo_f(unsigned u) {
    union { unsigned u; float f; } c; c.u = u << 16; return c.f;
}
__device__ __forceinline__ float hi_f(unsigned u) {
    union { unsigned u; float f; } c; c.u = u & 0xffff0000u; return c.f;
}

__global__ void __launch_bounds__(NTHR) gru_persistent(
    const float* __restrict__ x,   // [B, T, D]
    const float* __restrict__ W1,  // [2D, 2D]
    const float* __restrict__ b1,  // [2D]
    const float* __restrict__ W2,  // [D, 2D]
    const float* __restrict__ b2,  // [D]
    float* __restrict__ out,       // [B, T, D]
    float* __restrict__ ws)
{
    // LDS: 32+32+32+8+16 KB + stash = ~120.3 KB
    __shared__ unsigned w1x[O_PER * 512];   // x-part of W1 slice, bf16 pairs
    __shared__ unsigned w1m[O_PER * 512];   // mem-part of W1 slice
    __shared__ unsigned w2s[C_PER * 1024];  // W2 slice, bf16 pairs
    __shared__ unsigned mstage[RPG * 512];  // staged mem(t-1), bf16 pairs
    __shared__ unsigned hstage[RPG * 1024]; // staged h(t), bf16 pairs
    __shared__ float    stash[O_PER * RPG]; // intra-WG result exchange

    const int g   = blockIdx.x;
    const int tid = threadIdx.x;
    const int gl  = g & (GWG - 1);   // id within group
    const int grp = g >> 7;          // group 0/1
    const int b0  = grp * RPG;       // first batch row of this group

    unsigned* wsu     = (unsigned*)ws;
    unsigned* ctrbase = wsu + (size_t)grp * NCTR * CTR_STRIDE;   // 2*64 ctrs total
    unsigned* memg    = wsu + 2 * NCTR * CTR_STRIDE;             // [8][512] bf16 pairs
    unsigned* hg      = memg + BATCH * 512;                      // [8][1024] bf16 pairs

    // ---- stage weights into LDS as bf16 pairs (once) ----
    {
        // W1 slice: rows [gl*16, +16), each 2048 wide -> 1024 pairs
        for (int it = 0; it < 16; ++it) {
            int slot = it * NTHR + tid;          // 0..16383
            int i = slot >> 10, p = slot & 1023; // row-local, pair idx
            int k = 2 * p;
            const float* src = W1 + ((size_t)(gl * O_PER + i)) * TWO_D + k;
            unsigned u = pack2(src[0], src[1]);
            if (p < 512) w1x[i * 512 + p]       = u;
            else         w1m[i * 512 + (p - 512)] = u;
        }
        // W2 slice: rows [gl*8, +8)
        for (int it = 0; it < 8; ++it) {
            int slot = it * NTHR + tid;          // 0..8191
            int i = slot >> 10, p = slot & 1023;
            int k = 2 * p;
            const float* src = W2 + ((size_t)(gl * C_PER + i)) * TWO_D + k;
            w2s[i * 1024 + p] = pack2(src[0], src[1]);
        }
    }
    if (g == 0 && tid < 2 * NCTR) st_agent_u(&wsu[tid * CTR_STRIDE], 0u);
    __syncthreads();

    // phase-1 mapping: 64 pairs (row, ol) x 16 k-lanes
    const int p1  = tid >> 4;
    const int s1  = tid & 15;
    const int pb1 = p1 & 3;          // row within group
    const int ol  = p1 >> 2;         // 0..15
    // phase-2 mapping: 32 pairs (row, cl) x 32 k-lanes
    const int p2  = tid >> 5;
    const int s2  = tid & 31;
    const int pb2 = p2 & 3;
    const int cl  = p2 >> 2;         // 0..7

    const float bias1 = b1[gl * O_PER + ol];
    const float bias2 = b2[gl * C_PER + cl];
    float mymem = 0.0f;              // fp32 recurrent state (s2==0 owners)

    const uint2* wx2 = (const uint2*)(w1x + (size_t)ol * 512);    // 256 uint2
    const uint4* wm4 = (const uint4*)(w1m + (size_t)ol * 512);    // 128 uint4
    const uint4* w24 = (const uint4*)(w2s + (size_t)cl * 1024);   // 256 uint4
    const uint4* mv4 = (const uint4*)(mstage + (size_t)pb1 * 512);
    const uint4* hv4 = (const uint4*)(hstage + (size_t)pb2 * 1024);

    // x-partial for step t (independent of mem) — prefetched during spin
    auto xpart = [&](int t) -> float {
        const float4* xv = (const float4*)(x + ((size_t)(b0 + pb1) * SEQ_T + t) * DIM);
        float a0 = 0.f, a1 = 0.f, a2 = 0.f, a3 = 0.f;
        #pragma unroll
        for (int j = 0; j < 16; ++j) {
            int f = j * 16 + s1;
            float4 xa = xv[f];
            uint2  w  = wx2[f];
            a0 += xa.x * lo_f(w.x); a1 += xa.y * hi_f(w.x);
            a2 += xa.z * lo_f(w.y); a3 += xa.w * hi_f(w.y);
        }
        return (a0 + a1) + (a2 + a3);
    };
    float axp = xpart(0);

    cg::this_grid().sync();   // once: orders ctr init + weight visibility

    unsigned bk = 0;
    for (int t = 0; t < SEQ_T; ++t) {
        // ---- stage mem(t-1) bf16 pairs into LDS ----
        if (t == 0) {
            mstage[tid] = 0u; mstage[tid + 1024] = 0u;
        } else {
            {
                int i = tid;          mstage[i] = ld_agent_u(&memg[(size_t)(b0 + (i >> 9)) * 512 + (i & 511)]);
            }
            {
                int i = tid + 1024;   mstage[i] = ld_agent_u(&memg[(size_t)(b0 + (i >> 9)) * 512 + (i & 511)]);
            }
        }
        __syncthreads();

        // ---- phase 1: h = gelu(x-part + mem-part + b1) ----
        {
            float a0 = 0.f, a1 = 0.f;
            #pragma unroll
            for (int j = 0; j < 8; ++j) {
                int f = j * 16 + s1;
                uint4 m = mv4[f], w = wm4[f];
                a0 += lo_f(m.x) * lo_f(w.x); a1 += hi_f(m.x) * hi_f(w.x);
                a0 += lo_f(m.y) * lo_f(w.y); a1 += hi_f(m.y) * hi_f(w.y);
                a0 += lo_f(m.z) * lo_f(w.z); a1 += hi_f(m.z) * hi_f(w.z);
                a0 += lo_f(m.w) * lo_f(w.w); a1 += hi_f(m.w) * hi_f(w.w);
            }
            float acc = axp + a0 + a1;
            acc += __shfl_xor(acc, 1);
            acc += __shfl_xor(acc, 2);
            acc += __shfl_xor(acc, 4);
            acc += __shfl_xor(acc, 8);
            if (s1 == 0) stash[ol * RPG + pb1] = gelu_erf(acc + bias1);
        }
        __syncthreads();
        // ---- pack + publish h (8 pairs x 4 rows per WG) ----
        if (tid < 32) {
            int pb = tid & 3, j = tid >> 2;    // j = 0..7
            unsigned u = pack2(stash[(2 * j) * RPG + pb], stash[(2 * j + 1) * RPG + pb]);
            st_agent_u(&hg[(size_t)(b0 + pb) * 1024 + gl * 8 + j], u);
        }
        __syncthreads();   // drain publish stores (vmcnt(0) per wave)
        if (tid == 0)
            __hip_atomic_fetch_add(&ctrbase[(gl & (NCTR - 1)) * CTR_STRIDE], 1u,
                                   __ATOMIC_RELAXED, SCOPE);
        ++bk;
        if (t + 1 < SEQ_T) axp = xpart(t + 1);   // overlap with arrival wait
        if (tid < 64) {
            const unsigned tgt = bk * GWG;
            for (;;) {
                unsigned v = ld_agent_u(&ctrbase[tid * CTR_STRIDE]);
                v += __shfl_xor(v, 1);  v += __shfl_xor(v, 2);
                v += __shfl_xor(v, 4);  v += __shfl_xor(v, 8);
                v += __shfl_xor(v, 16); v += __shfl_xor(v, 32);
                if (v >= tgt) break;
            }
        }
        __syncthreads();

        // ---- stage h(t) bf16 pairs into LDS ----
        #pragma unroll
        for (int k = 0; k < 4; ++k) {
            int i = k * NTHR + tid;
            hstage[i] = ld_agent_u(&hg[(size_t)(b0 + (i >> 10)) * 1024 + (i & 1023)]);
        }
        __syncthreads();

        // ---- phase 2: proposed = h @ W2.T + b2; gated update ----
        {
            float a0 = 0.f, a1 = 0.f;
            #pragma unroll
            for (int j = 0; j < 8; ++j) {
                int f = j * 32 + s2;
                uint4 h = hv4[f], w = w24[f];
                a0 += lo_f(h.x) * lo_f(w.x); a1 += hi_f(h.x) * hi_f(w.x);
                a0 += lo_f(h.y) * lo_f(w.y); a1 += hi_f(h.y) * hi_f(w.y);
                a0 += lo_f(h.z) * lo_f(w.z); a1 += hi_f(h.z) * hi_f(w.z);
                a0 += lo_f(h.w) * lo_f(w.w); a1 += hi_f(h.w) * hi_f(w.w);
            }
            float acc = a0 + a1;
            acc += __shfl_xor(acc, 1);
            acc += __shfl_xor(acc, 2);
            acc += __shfl_xor(acc, 4);
            acc += __shfl_xor(acc, 8);
            acc += __shfl_xor(acc, 16);
            if (s2 == 0) {
                float prop = acc + bias2;
                float gate = 1.0f / (1.0f + expf(-prop));
                mymem = mymem * (1.0f - gate) + prop * gate;
                out[((size_t)(b0 + pb2) * SEQ_T + t) * DIM + gl * C_PER + cl] = mymem;
                stash[pb2 * C_PER + cl] = mymem;
            }
        }
        __syncthreads();
        // ---- pack + publish mem (4 pairs x 4 rows per WG) ----
        if (tid < 16) {
            int pb = tid & 3, j = tid >> 2;    // j = 0..3
            unsigned u = pack2(stash[pb * C_PER + 2 * j], stash[pb * C_PER + 2 * j + 1]);
            st_agent_u(&memg[(size_t)(b0 + pb) * 512 + gl * 4 + j], u);
        }
        __syncthreads();
        if (tid == 0)
            __hip_atomic_fetch_add(&ctrbase[(gl & (NCTR - 1)) * CTR_STRIDE], 1u,
                                   __ATOMIC_RELAXED, SCOPE);
        ++bk;
        if (tid < 64) {
            const unsigned tgt = bk * GWG;
            for (;;) {
                unsigned v = ld_agent_u(&ctrbase[tid * CTR_STRIDE]);
                v += __shfl_xor(v, 1);  v += __shfl_xor(v, 2);
                v += __shfl_xor(v, 4);  v += __shfl_xor(v, 8);
                v += __shfl_xor(v, 16); v += __shfl_xor(v, 32);
                if (v >= tgt) break;
            }
        }
        __syncthreads();
    }
}

extern "C" void kernel_launch(void* const* d_in, const int* in_sizes, int n_in,
                              void* d_out, int out_size, void* d_ws, size_t ws_size,
                              hipStream_t stream) {
    const float* x  = (const float*)d_in[0];
    const float* W1 = (const float*)d_in[1];
    const float* b1 = (const float*)d_in[2];
    const float* W2 = (const float*)d_in[3];
    const float* b2 = (const float*)d_in[4];
    float* out = (float*)d_out;
    float* ws  = (float*)d_ws;

    void* args[] = {(void*)&x, (void*)&W1, (void*)&b1, (void*)&W2, (void*)&b2,
                    (void*)&out, (void*)&ws};
    (void)hipLaunchCooperativeKernel((const void*)gru_persistent,
                                     dim3(NWG), dim3(NTHR), args, 0, stream);
}